// Round 7
// baseline (298.314 us; speedup 1.0000x reference)
//
#include <hip/hip_runtime.h>
#include <math.h>

#define N_NODE 20000
#define N_EDGE 200000
#define EMBED 256
#define PAIR 128
#define HEADS 16
#define HEAD_DIM 16
#define SCALING 0.25f
#define LNEPS 1e-5f

typedef unsigned short u16;
typedef unsigned int u32;
typedef __attribute__((ext_vector_type(8))) short bf16x8;
typedef __attribute__((ext_vector_type(4))) float f32x4;

// ---------------- workspace layout (bytes) ----------------
#define WS_QKV   0            // qk_bf  : 20000*512*2  = 20,480,000 (q scaled)
#define WS_QN    20480000     // qn_bf  : 20000*256*2  = 10,240,000
#define WS_WBF   30720000     // WbfAll : 640*256*2    =    327,680 (Wq|Wk|WV2|pad)
#define WS_WW    31047680     // WW_bf  : 16*128*2     =      4,096
#define WS_C0    31051776     // c0     : 16*4 (pad 64)
#define WS_C1    31051840     // c1     : 16*4 (pad 64)
#define WS_BIAS  31051904     // bias   : 200000*16*4  = 12,800,000 (edge order)
#define WS_VW    43851904     // vw     : 20000*48*4   =  3,840,000 (f32, from GEMM)
#define WS_CNT   47691904     // counts : 20000*4
#define WS_CUR   47771904     // cursor : 20000*4
#define WS_OFF   47851904     // off    : 20001*4 (pad to 80064)
#define WS_DE    47931968     // de     : 200000*8 {dst,e} in pos order

__device__ __forceinline__ u16 f2bf(float f) {
  u32 u = __float_as_uint(f);
  u32 r = (u + 0x7FFFu + ((u >> 16) & 1u)) >> 16;
  return (u16)r;
}
__device__ __forceinline__ float bl(u32 u) { return __uint_as_float(u << 16); }
__device__ __forceinline__ float bh(u32 u) { return __uint_as_float(u & 0xFFFF0000u); }

__device__ __forceinline__ float dot8(uint4 a, uint4 b) {
  float s = bl(a.x) * bl(b.x) + bh(a.x) * bh(b.x);
  s += bl(a.y) * bl(b.y) + bh(a.y) * bh(b.y);
  s += bl(a.z) * bl(b.z) + bh(a.z) * bh(b.z);
  s += bl(a.w) * bl(b.w) + bh(a.w) * bh(b.w);
  return s;
}

// ==================================================================
// K1: block-partitioned — [0,5000): ln_qn (+zero counts/cur);
// [5000,5128): wcvt (Wq,Wk); 5128: prep (WW,c0,c1);
// [5129,5177): WV2 compose (1 block/row); [5177,5182): zero-pad.
__global__ __launch_bounds__(256) void k1_pre_kernel(
    const float* __restrict__ query, const float* __restrict__ ln_w,
    const float* __restrict__ ln_b, u16* __restrict__ qn,
    int* __restrict__ counts, int* __restrict__ cur,
    const float* __restrict__ Wq, const float* __restrict__ Wk,
    const float* __restrict__ Wv, u16* __restrict__ WbfAll,
    const float* __restrict__ pln_w, const float* __restrict__ pln_b,
    const float* __restrict__ Wb, const float* __restrict__ bb,
    u16* __restrict__ WWbf, float* __restrict__ c0, float* __restrict__ c1,
    const float* __restrict__ Wf1, const float* __restrict__ Wf2,
    const float* __restrict__ Wf3) {
  int bid = blockIdx.x;
  int t = threadIdx.x;
  if (bid < 5000) {
    int z = bid * 256 + t;
    if (z < N_NODE) { counts[z] = 0; cur[z] = 0; }
    int node = bid * 4 + (t >> 6);
    int lane = t & 63;
    float4 a = *(const float4*)(query + (size_t)node * EMBED + lane * 4);
    float s = a.x + a.y + a.z + a.w;
    float s2 = a.x * a.x + a.y * a.y + a.z * a.z + a.w * a.w;
    #pragma unroll
    for (int off = 32; off > 0; off >>= 1) {
      s += __shfl_xor(s, off);
      s2 += __shfl_xor(s2, off);
    }
    float m = s * (1.0f / EMBED);
    float r = rsqrtf(s2 * (1.0f / EMBED) - m * m + LNEPS);
    float4 w4 = *(const float4*)(ln_w + lane * 4);
    float4 b4 = *(const float4*)(ln_b + lane * 4);
    ushort4 st;
    st.x = f2bf((a.x - m) * r * w4.x + b4.x);
    st.y = f2bf((a.y - m) * r * w4.y + b4.y);
    st.z = f2bf((a.z - m) * r * w4.z + b4.z);
    st.w = f2bf((a.w - m) * r * w4.w + b4.w);
    *(ushort4*)(qn + (size_t)node * EMBED + lane * 4) = st;
  } else if (bid < 5128) {
    int g4 = (bid - 5000) * 256 + t;
    int idx = g4 * 4;  // 0..131071 floats over {Wq,Wk}
    const float* src = (idx < 65536) ? Wq : Wk;
    float4 v = *(const float4*)(src + (idx & 65535));
    ushort4 st = {f2bf(v.x), f2bf(v.y), f2bf(v.z), f2bf(v.w)};
    *(ushort4*)(WbfAll + idx) = st;
  } else if (bid == 5128) {
    if (t < 64) {
      int l = t;
      for (int h = 0; h < HEADS; h++) {
        int i0 = l * 2;
        float wb0 = Wb[h * PAIR + i0], wb1 = Wb[h * PAIR + i0 + 1];
        float ww0 = pln_w[i0] * wb0, ww1 = pln_w[i0 + 1] * wb1;
        WWbf[h * PAIR + i0] = f2bf(ww0);
        WWbf[h * PAIR + i0 + 1] = f2bf(ww1);
        float s1 = ww0 + ww1;
        float s0 = pln_b[i0] * wb0 + pln_b[i0 + 1] * wb1;
        #pragma unroll
        for (int off = 32; off > 0; off >>= 1) {
          s1 += __shfl_xor(s1, off);
          s0 += __shfl_xor(s0, off);
        }
        if (l == 0) {
          c1[h] = s1;
          c0[h] = s0 + bb[h];
        }
      }
    }
  } else if (bid < 5177) {
    // WV2 row j: WV2[j, k=t] = sum_d Wv[h*16+d, k] * Wf_c[h*16+d]
    int j = bid - 5129;
    int h = j / 3, c = j - h * 3;
    const float* wf = (c == 0) ? Wf1 : ((c == 1) ? Wf2 : Wf3);
    float s = 0.f;
    #pragma unroll
    for (int d = 0; d < 16; d++)
      s += Wv[(size_t)(h * 16 + d) * 256 + t] * wf[h * 16 + d];
    WbfAll[(size_t)(512 + j) * 256 + t] = f2bf(s);
  } else {
    // zero-pad rows 560..639
    int base = (bid - 5177) * 512 + t * 2;
    uint4* p = (uint4*)(WbfAll + (size_t)560 * 256);
    uint4 z4 = {0u, 0u, 0u, 0u};
    p[base] = z4;
    p[base + 1] = z4;
  }
}

// ==================================================================
// K2: fused GEMM + hist + pair_bias with INTERLEAVED roles so each CU's
// resident set mixes compute-bound GEMM blocks with BW-bound bias blocks.
//   role GEMM (785): bid%6==0 (782) + bids [4692,4695) (3)
//   role hist (782): first 782 non-multiples-of-6
//   role bias (3128, 3125 active): remaining non-multiples
// GEMM now BK=32 (8 K-iters): LDS 20,480B; block LDS = bias's 22,400B
// -> 7 blocks/CU (was 4 at 36,864B). K-chunk order per quad unchanged
// (it*32+quad*8 == old it*64+s*32+quad*8 sequence) -> bit-identical.
#define BKP 40
#define PP 136
__global__ __launch_bounds__(256, 2) void k2_gemm_hist_bias_kernel(
    const u16* __restrict__ qn, const u16* __restrict__ WbfAll,
    u16* __restrict__ qkv, float* __restrict__ vw,
    const int* __restrict__ edge_index, int* __restrict__ counts,
    const float* __restrict__ pair, const u16* __restrict__ WWbf,
    const float* __restrict__ c0g, const float* __restrict__ c1g,
    float* __restrict__ bias) {
  __shared__ u16 smem[11200];  // 22,400 B (union of GEMM 20,480 / bias 22,400)
  int bid = blockIdx.x;
  int t = threadIdx.x;
  int role, idx;
  if (bid >= 4692) {
    role = 0; idx = 782 + (bid - 4692);
  } else if (bid % 6 == 0) {
    role = 0; idx = bid / 6;
  } else {
    int nm = bid - bid / 6 - 1;  // index among non-multiples of 6
    if (nm < 782) { role = 1; idx = nm; }
    else          { role = 2; idx = nm - 782; }
  }
  if (role == 1) {
    int e = idx * 256 + t;
    if (e < N_EDGE) atomicAdd(&counts[edge_index[e * 2]], 1);
    return;
  }
  if (role == 2) {
    // ---- pair_bias ----
    int e0 = idx * 64;
    if (e0 >= N_EDGE) return;
    u16* Ps = smem;                         // 64*PP u16
    u16* WWs = smem + 64 * PP;              // 16*PP u16
    float* ms = (float*)(smem + 80 * PP);   // 64 f
    float* rs = ms + 64;                    // 64 f
    float* c0s = rs + 64;                   // 16 f
    float* c1s = c0s + 16;                  // 16 f
    int wv = t >> 6, lane = t & 63;
    int quad = lane >> 4, l16 = lane & 15;
    #pragma unroll
    for (int j = 0; j < 8; j++) {
      int L = j * 256 + t;
      int row = L >> 5, slot = L & 31;
      float4 p = *(const float4*)(pair + (size_t)(e0 + row) * PAIR + slot * 4);
      ushort4 st = {f2bf(p.x), f2bf(p.y), f2bf(p.z), f2bf(p.w)};
      *(ushort4*)(&Ps[row * PP + slot * 4]) = st;
    }
    #pragma unroll
    for (int j = 0; j < 2; j++) {
      int L = j * 256 + t;
      int row = L >> 5, slot = L & 31;
      ushort4 w = *(const ushort4*)(WWbf + row * PAIR + slot * 4);
      *(ushort4*)(&WWs[row * PP + slot * 4]) = w;
    }
    if (t < 16) {
      c0s[t] = c0g[t];
      c1s[t] = c1g[t];
    }
    __syncthreads();
    {
      int row = t >> 2, qq = t & 3;
      float s = 0.f, s2 = 0.f;
      #pragma unroll
      for (int jj = 0; jj < 8; jj++) {
        ushort4 u = *(const ushort4*)(&Ps[row * PP + (qq * 8 + jj) * 4]);
        float x0 = __uint_as_float((u32)u.x << 16);
        float x1 = __uint_as_float((u32)u.y << 16);
        float x2 = __uint_as_float((u32)u.z << 16);
        float x3 = __uint_as_float((u32)u.w << 16);
        s += x0 + x1 + x2 + x3;
        s2 += x0 * x0 + x1 * x1 + x2 * x2 + x3 * x3;
      }
      s += __shfl_xor(s, 1); s += __shfl_xor(s, 2);
      s2 += __shfl_xor(s2, 1); s2 += __shfl_xor(s2, 2);
      if (qq == 0) {
        float m = s * (1.0f / PAIR);
        ms[row] = m;
        rs[row] = rsqrtf(s2 * (1.0f / PAIR) - m * m + LNEPS);
      }
    }
    __syncthreads();
    f32x4 acc = (f32x4){0.f, 0.f, 0.f, 0.f};
    #pragma unroll
    for (int sk = 0; sk < 4; sk++) {
      int ko = sk * 32 + quad * 8;
      bf16x8 a = *(const bf16x8*)(&Ps[(wv * 16 + l16) * PP + ko]);
      bf16x8 b = *(const bf16x8*)(&WWs[l16 * PP + ko]);
      acc = __builtin_amdgcn_mfma_f32_16x16x32_bf16(a, b, acc, 0, 0, 0);
    }
    #pragma unroll
    for (int r = 0; r < 4; r++) {
      int el = wv * 16 + quad * 4 + r;
      float bv = rs[el] * (acc[r] - ms[el] * c1s[l16]) + c0s[l16];
      bias[(size_t)(e0 + el) * HEADS + l16] = bv;
    }
    return;
  }
  // ---- GEMM (BK=32) ----
  u16* As = smem;                // 128*BKP u16 = 5120
  u16* Bs = smem + 128 * BKP;    // 128*BKP u16
  int bx = idx % 157, by = idx / 157;  // by in [0,5)
  int wv = t >> 6, lane = t & 63;
  int quad = lane >> 4, l16 = lane & 15;
  int row0 = bx * 128, col0 = by * 128;
  int mt = (wv >> 1) * 64, nt = (wv & 1) * 64;

  f32x4 acc[4][4];
  #pragma unroll
  for (int im = 0; im < 4; im++)
    #pragma unroll
    for (int in_ = 0; in_ < 4; in_++) acc[im][in_] = (f32x4){0.f, 0.f, 0.f, 0.f};

  for (int it = 0; it < 8; it++) {
    int k0 = it * 32;
    #pragma unroll
    for (int j = 0; j < 2; j++) {
      int L = j * 256 + t;          // 0..511
      int row = L >> 2, slot = L & 3;
      int ra = min(row0 + row, N_NODE - 1);
      uint4 va = *(const uint4*)(qn + (size_t)ra * 256 + k0 + slot * 8);
      *(uint4*)(&As[row * BKP + slot * 8]) = va;
      uint4 vb = *(const uint4*)(WbfAll + (size_t)(col0 + row) * 256 + k0 + slot * 8);
      *(uint4*)(&Bs[row * BKP + slot * 8]) = vb;
    }
    __syncthreads();
    {
      int ko = quad * 8;
      bf16x8 af[4], bf[4];
      #pragma unroll
      for (int im = 0; im < 4; im++)
        af[im] = *(const bf16x8*)(&As[(mt + im * 16 + l16) * BKP + ko]);
      #pragma unroll
      for (int in_ = 0; in_ < 4; in_++)
        bf[in_] = *(const bf16x8*)(&Bs[(nt + in_ * 16 + l16) * BKP + ko]);
      #pragma unroll
      for (int im = 0; im < 4; im++)
        #pragma unroll
        for (int in_ = 0; in_ < 4; in_++)
          acc[im][in_] = __builtin_amdgcn_mfma_f32_16x16x32_bf16(
              af[im], bf[in_], acc[im][in_], 0, 0, 0);
    }
    __syncthreads();
  }
  #pragma unroll
  for (int im = 0; im < 4; im++) {
    #pragma unroll
    for (int in_ = 0; in_ < 4; in_++) {
      int gcol = col0 + nt + in_ * 16 + l16;
      float scale = (gcol < 256) ? SCALING : 1.0f;
      #pragma unroll
      for (int r = 0; r < 4; r++) {
        int grow = row0 + mt + im * 16 + quad * 4 + r;
        if (grow < N_NODE) {
          if (gcol < 512) {
            qkv[(size_t)grow * 512 + gcol] = f2bf(acc[im][in_][r] * scale);
          } else if (gcol < 560) {
            vw[(size_t)grow * 48 + (gcol - 512)] = acc[im][in_][r];
          }
        }
      }
    }
  }
}

// ==================================================================
// K3: exclusive scan of counts (20000) -> off[0..20000]. Single block.
__global__ __launch_bounds__(1024) void scan_kernel(
    const int* __restrict__ counts, int* __restrict__ off) {
  __shared__ int part[1024];
  int t = threadIdx.x;
  int loc[20];
  int s = 0;
  #pragma unroll
  for (int i = 0; i < 20; i++) {
    int idx = t * 20 + i;
    int v = (idx < N_NODE) ? counts[idx] : 0;
    loc[i] = s;
    s += v;
  }
  part[t] = s;
  __syncthreads();
  int x = s;
  for (int o = 1; o < 1024; o <<= 1) {
    int y = (t >= o) ? part[t - o] : 0;
    __syncthreads();
    x += y;
    part[t] = x;
    __syncthreads();
  }
  int excl = x - s;
  #pragma unroll
  for (int i = 0; i < 20; i++) {
    int idx = t * 20 + i;
    if (idx < N_NODE) off[idx] = excl + loc[i];
  }
  if (t == 0) off[N_NODE] = N_EDGE;
}

// ==================================================================
// K4: scatter only — de[pos] = {dst, e}.
__global__ __launch_bounds__(256) void k4_scatter_kernel(
    const int* __restrict__ edge_index, const int* __restrict__ off,
    int* __restrict__ cur, int2* __restrict__ de) {
  int e = blockIdx.x * 256 + threadIdx.x;
  if (e < N_EDGE) {
    int src = edge_index[e * 2 + 0];
    int dst = edge_index[e * 2 + 1];
    int pos = off[src] + atomicAdd(&cur[src], 1);
    de[pos] = make_int2(dst, e);
  }
}

// ==================================================================
// K5: segmented attention, single pass. qk stride 512; vw f32 from GEMM.
__global__ __launch_bounds__(256) void seg_attn_kernel(
    const u16* __restrict__ qkv, const float* __restrict__ bias,
    const int* __restrict__ off, const int2* __restrict__ de,
    const float* __restrict__ vw, const float* __restrict__ edge_diff,
    const float* __restrict__ bf1, const float* __restrict__ bf2,
    const float* __restrict__ bf3, float* __restrict__ out) {
  int wv = threadIdx.x >> 6, lane = threadIdx.x & 63;
  int src = blockIdx.x * 4 + wv;
  int h = lane & 15, eslot = lane >> 4;
  int lo = off[src];
  int deg = off[src + 1] - lo;
  const uint4* qp = (const uint4*)(qkv + (size_t)src * 512 + h * 16);
  uint4 q0 = qp[0], q1 = qp[1];
  float exsum = 0.f, a0 = 0.f, a1 = 0.f, a2 = 0.f;
  for (int ei = eslot; ei < deg; ei += 4) {
    int2 d_e = de[lo + ei];
    const uint4* kp = (const uint4*)(qkv + (size_t)d_e.x * 512 + 256 + h * 16);
    float d = dot8(q0, kp[0]) + dot8(q1, kp[1]);
    float ex = __expf(d + bias[(size_t)d_e.y * HEADS + h]);
    exsum += ex;
    const float* vp = vw + (size_t)d_e.x * 48 + h * 3;
    const float* dp = edge_diff + (size_t)d_e.y * 3;
    a0 += ex * vp[0] * dp[0];
    a1 += ex * vp[1] * dp[1];
    a2 += ex * vp[2] * dp[2];
  }
  exsum += __shfl_xor(exsum, 16);
  exsum += __shfl_xor(exsum, 32);
  float rden = (exsum > 0.f) ? 1.0f / exsum : 0.f;
  a0 *= rden; a1 *= rden; a2 *= rden;
  #pragma unroll
  for (int o = 1; o < 64; o <<= 1) {
    a0 += __shfl_xor(a0, o);
    a1 += __shfl_xor(a1, o);
    a2 += __shfl_xor(a2, o);
  }
  if (lane == 0) {
    out[src * 3 + 0] = a0 + bf1[0];
    out[src * 3 + 1] = a1 + bf2[0];
    out[src * 3 + 2] = a2 + bf3[0];
  }
}

// ==================================================================
extern "C" void kernel_launch(void* const* d_in, const int* in_sizes, int n_in,
                              void* d_out, int out_size, void* d_ws,
                              size_t ws_size, hipStream_t stream) {
  const float* query      = (const float*)d_in[0];
  const int*   edge_index = (const int*)d_in[1];
  const float* edge_diff  = (const float*)d_in[2];
  const float* pair       = (const float*)d_in[3];
  const float* ln_w       = (const float*)d_in[4];
  const float* ln_b       = (const float*)d_in[5];
  const float* pln_w      = (const float*)d_in[6];
  const float* pln_b      = (const float*)d_in[7];
  const float* Wq         = (const float*)d_in[8];
  const float* Wk         = (const float*)d_in[9];
  const float* Wv         = (const float*)d_in[10];
  const float* Wb         = (const float*)d_in[11];
  const float* bb         = (const float*)d_in[12];
  const float* Wf1        = (const float*)d_in[13];
  const float* bf1        = (const float*)d_in[14];
  const float* Wf2        = (const float*)d_in[15];
  const float* bf2        = (const float*)d_in[16];
  const float* Wf3        = (const float*)d_in[17];
  const float* bf3        = (const float*)d_in[18];

  char* ws = (char*)d_ws;
  u16*   qkv   = (u16*)(ws + WS_QKV);
  u16*   qn    = (u16*)(ws + WS_QN);
  u16*   WbfAll= (u16*)(ws + WS_WBF);
  u16*   WWbf  = (u16*)(ws + WS_WW);
  float* c0    = (float*)(ws + WS_C0);
  float* c1    = (float*)(ws + WS_C1);
  float* bias  = (float*)(ws + WS_BIAS);
  float* vw    = (float*)(ws + WS_VW);
  int*   counts= (int*)(ws + WS_CNT);
  int*   cur   = (int*)(ws + WS_CUR);
  int*   off   = (int*)(ws + WS_OFF);
  int2*  de    = (int2*)(ws + WS_DE);
  float* out   = (float*)d_out;

  k1_pre_kernel<<<5182, 256, 0, stream>>>(query, ln_w, ln_b, qn, counts, cur,
                                          Wq, Wk, Wv, WbfAll, pln_w, pln_b,
                                          Wb, bb, WWbf, c0, c1, Wf1, Wf2, Wf3);
  k2_gemm_hist_bias_kernel<<<4695, 256, 0, stream>>>(
      qn, WbfAll, qkv, vw, edge_index, counts, pair, WWbf, c0, c1, bias);
  scan_kernel<<<1, 1024, 0, stream>>>(counts, off);
  k4_scatter_kernel<<<782, 256, 0, stream>>>(edge_index, off, cur, de);
  seg_attn_kernel<<<N_NODE / 4, 256, 0, stream>>>(qkv, bias, off, de, vw,
                                                  edge_diff, bf1, bf2, bf3,
                                                  out);
}

// Round 8
// 292.002 us; speedup vs baseline: 1.0216x; 1.0216x over previous
//
#include <hip/hip_runtime.h>
#include <math.h>

#define N_NODE 20000
#define N_EDGE 200000
#define EMBED 256
#define PAIR 128
#define HEADS 16
#define HEAD_DIM 16
#define SCALING 0.25f
#define LNEPS 1e-5f

typedef unsigned short u16;
typedef unsigned int u32;
typedef __attribute__((ext_vector_type(8))) short bf16x8;
typedef __attribute__((ext_vector_type(4))) float f32x4;

// ---------------- workspace layout (bytes) ----------------
#define WS_QKV   0            // qk_bf  : 20000*512*2  = 20,480,000 (q scaled)
#define WS_QN    20480000     // qn_bf  : 20000*256*2  = 10,240,000
#define WS_WBF   30720000     // WbfAll : 640*256*2    =    327,680 (Wq|Wk|WV2|pad)
#define WS_BIAS  31051904     // bias   : 200000*16*4  = 12,800,000 (edge order)
#define WS_VW    43851904     // vw     : 20000*48*4   =  3,840,000 (f32, from GEMM)
#define WS_CNT   47691904     // counts : 20000*4
#define WS_CUR   47771904     // cursor : 20000*4 (contiguous -> one memset)
#define WS_OFF   47851904     // off    : 20001*4 (pad to 80064)
#define WS_DE    47931968     // de     : 200000*8 {dst,e} in pos order

__device__ __forceinline__ u16 f2bf(float f) {
  u32 u = __float_as_uint(f);
  u32 r = (u + 0x7FFFu + ((u >> 16) & 1u)) >> 16;
  return (u16)r;
}
__device__ __forceinline__ float bl(u32 u) { return __uint_as_float(u << 16); }
__device__ __forceinline__ float bh(u32 u) { return __uint_as_float(u & 0xFFFF0000u); }

__device__ __forceinline__ float dot8(uint4 a, uint4 b) {
  float s = bl(a.x) * bl(b.x) + bh(a.x) * bh(b.x);
  s += bl(a.y) * bl(b.y) + bh(a.y) * bh(b.y);
  s += bl(a.z) * bl(b.z) + bh(a.z) * bh(b.z);
  s += bl(a.w) * bl(b.w) + bh(a.w) * bh(b.w);
  return s;
}

#define PP 136

// ==================================================================
// K1: all BW-bound / latency-bound work, no MFMA register pressure
// except the tiny per-block bias MFMA (4 AGPRs).
//   [0,5000):    ln_qn
//   [5000,5128): wcvt (Wq,Wk -> WbfAll)
//   [5128,5176): WV2 compose (1 block/row)
//   [5176,5181): zero-pad WbfAll rows 560..639
//   [5181,5963): hist (counts pre-zeroed by memsetAsync)
//   [5963,9088): pair_bias, SELF-SUFFICIENT: each block recomputes
//                WW/c0/c1 from Wb/pln_w/pln_b/bb (L3-hot, parallel
//                over 256 threads) -> no dependency on other blocks.
__global__ __launch_bounds__(256) void k1_pre_hist_bias_kernel(
    const float* __restrict__ query, const float* __restrict__ ln_w,
    const float* __restrict__ ln_b, u16* __restrict__ qn,
    const float* __restrict__ Wq, const float* __restrict__ Wk,
    const float* __restrict__ Wv, u16* __restrict__ WbfAll,
    const float* __restrict__ pln_w, const float* __restrict__ pln_b,
    const float* __restrict__ Wb, const float* __restrict__ bb,
    const float* __restrict__ Wf1, const float* __restrict__ Wf2,
    const float* __restrict__ Wf3, const int* __restrict__ edge_index,
    int* __restrict__ counts, const float* __restrict__ pair,
    float* __restrict__ bias) {
  __shared__ u16 smem[11200];  // 22,400 B (bias blocks only)
  int bid = blockIdx.x;
  int t = threadIdx.x;
  if (bid < 5000) {
    int node = bid * 4 + (t >> 6);
    int lane = t & 63;
    float4 a = *(const float4*)(query + (size_t)node * EMBED + lane * 4);
    float s = a.x + a.y + a.z + a.w;
    float s2 = a.x * a.x + a.y * a.y + a.z * a.z + a.w * a.w;
    #pragma unroll
    for (int off = 32; off > 0; off >>= 1) {
      s += __shfl_xor(s, off);
      s2 += __shfl_xor(s2, off);
    }
    float m = s * (1.0f / EMBED);
    float r = rsqrtf(s2 * (1.0f / EMBED) - m * m + LNEPS);
    float4 w4 = *(const float4*)(ln_w + lane * 4);
    float4 b4 = *(const float4*)(ln_b + lane * 4);
    ushort4 st;
    st.x = f2bf((a.x - m) * r * w4.x + b4.x);
    st.y = f2bf((a.y - m) * r * w4.y + b4.y);
    st.z = f2bf((a.z - m) * r * w4.z + b4.z);
    st.w = f2bf((a.w - m) * r * w4.w + b4.w);
    *(ushort4*)(qn + (size_t)node * EMBED + lane * 4) = st;
  } else if (bid < 5128) {
    int g4 = (bid - 5000) * 256 + t;
    int idx = g4 * 4;  // 0..131071 floats over {Wq,Wk}
    const float* src = (idx < 65536) ? Wq : Wk;
    float4 v = *(const float4*)(src + (idx & 65535));
    ushort4 st = {f2bf(v.x), f2bf(v.y), f2bf(v.z), f2bf(v.w)};
    *(ushort4*)(WbfAll + idx) = st;
  } else if (bid < 5176) {
    // WV2 row j: WV2[j, k=t] = sum_d Wv[h*16+d, k] * Wf_c[h*16+d]
    int j = bid - 5128;
    int h = j / 3, c = j - h * 3;
    const float* wf = (c == 0) ? Wf1 : ((c == 1) ? Wf2 : Wf3);
    float s = 0.f;
    #pragma unroll
    for (int d = 0; d < 16; d++)
      s += Wv[(size_t)(h * 16 + d) * 256 + t] * wf[h * 16 + d];
    WbfAll[(size_t)(512 + j) * 256 + t] = f2bf(s);
  } else if (bid < 5181) {
    // zero-pad rows 560..639
    int base = (bid - 5176) * 512 + t * 2;
    uint4* p = (uint4*)(WbfAll + (size_t)560 * 256);
    uint4 z4 = {0u, 0u, 0u, 0u};
    p[base] = z4;
    p[base + 1] = z4;
  } else if (bid < 5963) {
    int e = (bid - 5181) * 256 + t;
    if (e < N_EDGE) atomicAdd(&counts[edge_index[e * 2]], 1);
  } else {
    // ---- pair_bias, self-sufficient ----
    int e0 = (bid - 5963) * 64;
    u16* Ps = smem;                         // 64*PP u16
    u16* WWs = smem + 64 * PP;              // 16*PP u16
    float* ms = (float*)(smem + 80 * PP);   // 64 f
    float* rs = ms + 64;                    // 64 f
    float* c0s = rs + 64;                   // 16 f
    float* c1s = c0s + 16;                  // 16 f
    int wv = t >> 6, lane = t & 63;
    int quad = lane >> 4, l16 = lane & 15;
    // stage pair -> LDS (bf16)
    #pragma unroll
    for (int j = 0; j < 8; j++) {
      int L = j * 256 + t;
      int row = L >> 5, slot = L & 31;
      float4 p = *(const float4*)(pair + (size_t)(e0 + row) * PAIR + slot * 4);
      ushort4 st = {f2bf(p.x), f2bf(p.y), f2bf(p.z), f2bf(p.w)};
      *(ushort4*)(&Ps[row * PP + slot * 4]) = st;
    }
    // self-prep: h = t>>4, 16 threads/head, 8 elems each
    {
      int h = t >> 4, i0 = (t & 15) * 8;
      float4 wbA = *(const float4*)(Wb + h * PAIR + i0);
      float4 wbB = *(const float4*)(Wb + h * PAIR + i0 + 4);
      float4 pwA = *(const float4*)(pln_w + i0);
      float4 pwB = *(const float4*)(pln_w + i0 + 4);
      float4 pbA = *(const float4*)(pln_b + i0);
      float4 pbB = *(const float4*)(pln_b + i0 + 4);
      float w0 = pwA.x * wbA.x, w1 = pwA.y * wbA.y;
      float w2 = pwA.z * wbA.z, w3 = pwA.w * wbA.w;
      float w4_ = pwB.x * wbB.x, w5 = pwB.y * wbB.y;
      float w6 = pwB.z * wbB.z, w7 = pwB.w * wbB.w;
      ushort4 sA = {f2bf(w0), f2bf(w1), f2bf(w2), f2bf(w3)};
      ushort4 sB = {f2bf(w4_), f2bf(w5), f2bf(w6), f2bf(w7)};
      *(ushort4*)(&WWs[h * PP + i0]) = sA;
      *(ushort4*)(&WWs[h * PP + i0 + 4]) = sB;
      float s1 = w0 + w1 + w2 + w3 + w4_ + w5 + w6 + w7;
      float s0 = pbA.x * wbA.x + pbA.y * wbA.y + pbA.z * wbA.z + pbA.w * wbA.w
               + pbB.x * wbB.x + pbB.y * wbB.y + pbB.z * wbB.z + pbB.w * wbB.w;
      #pragma unroll
      for (int off = 8; off > 0; off >>= 1) {
        s1 += __shfl_xor(s1, off);
        s0 += __shfl_xor(s0, off);
      }
      if ((t & 15) == 0) {
        c1s[h] = s1;
        c0s[h] = s0 + bb[h];
      }
    }
    __syncthreads();
    {
      int row = t >> 2, qq = t & 3;
      float s = 0.f, s2 = 0.f;
      #pragma unroll
      for (int jj = 0; jj < 8; jj++) {
        ushort4 u = *(const ushort4*)(&Ps[row * PP + (qq * 8 + jj) * 4]);
        float x0 = __uint_as_float((u32)u.x << 16);
        float x1 = __uint_as_float((u32)u.y << 16);
        float x2 = __uint_as_float((u32)u.z << 16);
        float x3 = __uint_as_float((u32)u.w << 16);
        s += x0 + x1 + x2 + x3;
        s2 += x0 * x0 + x1 * x1 + x2 * x2 + x3 * x3;
      }
      s += __shfl_xor(s, 1); s += __shfl_xor(s, 2);
      s2 += __shfl_xor(s2, 1); s2 += __shfl_xor(s2, 2);
      if (qq == 0) {
        float m = s * (1.0f / PAIR);
        ms[row] = m;
        rs[row] = rsqrtf(s2 * (1.0f / PAIR) - m * m + LNEPS);
      }
    }
    __syncthreads();
    f32x4 acc = (f32x4){0.f, 0.f, 0.f, 0.f};
    #pragma unroll
    for (int sk = 0; sk < 4; sk++) {
      int ko = sk * 32 + quad * 8;
      bf16x8 a = *(const bf16x8*)(&Ps[(wv * 16 + l16) * PP + ko]);
      bf16x8 b = *(const bf16x8*)(&WWs[l16 * PP + ko]);
      acc = __builtin_amdgcn_mfma_f32_16x16x32_bf16(a, b, acc, 0, 0, 0);
    }
    #pragma unroll
    for (int r = 0; r < 4; r++) {
      int el = wv * 16 + quad * 4 + r;
      float bv = rs[el] * (acc[r] - ms[el] * c1s[l16]) + c0s[l16];
      bias[(size_t)(e0 + el) * HEADS + l16] = bv;
    }
  }
}

// ==================================================================
// K2: [0,785): GEMM C = qn @ [Wq^T|Wk^T|WV2] (BK=32, bit-identical
// accumulation order); bid 785: exclusive scan of counts (counts are
// complete at the K1->K2 boundary; scan hides under the GEMM blocks).
#define BKP 40
__global__ __launch_bounds__(256, 2) void k2_gemm_scan_kernel(
    const u16* __restrict__ qn, const u16* __restrict__ WbfAll,
    u16* __restrict__ qkv, float* __restrict__ vw,
    const int* __restrict__ counts, int* __restrict__ off) {
  __shared__ u16 smem[10240];  // 20,480 B
  int bid = blockIdx.x;
  int t = threadIdx.x;
  if (bid == 785) {
    int* part = (int*)smem;
    int i0 = t * 79;
    int i1 = i0 + 79; if (i1 > N_NODE) i1 = N_NODE;
    int s = 0;
    for (int i = i0; i < i1; i++) s += counts[i];
    part[t] = s;
    __syncthreads();
    int x = s;
    for (int o = 1; o < 256; o <<= 1) {
      int y = (t >= o) ? part[t - o] : 0;
      __syncthreads();
      x += y;
      part[t] = x;
      __syncthreads();
    }
    int run = x - s;
    for (int i = i0; i < i1; i++) {
      off[i] = run;
      run += counts[i];
    }
    if (t == 255) off[N_NODE] = N_EDGE;
    return;
  }
  u16* As = smem;                // 128*BKP u16
  u16* Bs = smem + 128 * BKP;
  int bx = bid % 157, by = bid / 157;  // by in [0,5)
  int wv = t >> 6, lane = t & 63;
  int quad = lane >> 4, l16 = lane & 15;
  int row0 = bx * 128, col0 = by * 128;
  int mt = (wv >> 1) * 64, nt = (wv & 1) * 64;

  f32x4 acc[4][4];
  #pragma unroll
  for (int im = 0; im < 4; im++)
    #pragma unroll
    for (int in_ = 0; in_ < 4; in_++) acc[im][in_] = (f32x4){0.f, 0.f, 0.f, 0.f};

  for (int it = 0; it < 8; it++) {
    int k0 = it * 32;
    #pragma unroll
    for (int j = 0; j < 2; j++) {
      int L = j * 256 + t;          // 0..511
      int row = L >> 2, slot = L & 3;
      int ra = min(row0 + row, N_NODE - 1);
      uint4 va = *(const uint4*)(qn + (size_t)ra * 256 + k0 + slot * 8);
      *(uint4*)(&As[row * BKP + slot * 8]) = va;
      uint4 vb = *(const uint4*)(WbfAll + (size_t)(col0 + row) * 256 + k0 + slot * 8);
      *(uint4*)(&Bs[row * BKP + slot * 8]) = vb;
    }
    __syncthreads();
    {
      int ko = quad * 8;
      bf16x8 af[4], bf[4];
      #pragma unroll
      for (int im = 0; im < 4; im++)
        af[im] = *(const bf16x8*)(&As[(mt + im * 16 + l16) * BKP + ko]);
      #pragma unroll
      for (int in_ = 0; in_ < 4; in_++)
        bf[in_] = *(const bf16x8*)(&Bs[(nt + in_ * 16 + l16) * BKP + ko]);
      #pragma unroll
      for (int im = 0; im < 4; im++)
        #pragma unroll
        for (int in_ = 0; in_ < 4; in_++)
          acc[im][in_] = __builtin_amdgcn_mfma_f32_16x16x32_bf16(
              af[im], bf[in_], acc[im][in_], 0, 0, 0);
    }
    __syncthreads();
  }
  #pragma unroll
  for (int im = 0; im < 4; im++) {
    #pragma unroll
    for (int in_ = 0; in_ < 4; in_++) {
      int gcol = col0 + nt + in_ * 16 + l16;
      float scale = (gcol < 256) ? SCALING : 1.0f;
      #pragma unroll
      for (int r = 0; r < 4; r++) {
        int grow = row0 + mt + im * 16 + quad * 4 + r;
        if (grow < N_NODE) {
          if (gcol < 512) {
            qkv[(size_t)grow * 512 + gcol] = f2bf(acc[im][in_][r] * scale);
          } else if (gcol < 560) {
            vw[(size_t)grow * 48 + (gcol - 512)] = acc[im][in_][r];
          }
        }
      }
    }
  }
}

// ==================================================================
// K4: scatter only — de[pos] = {dst, e}.
__global__ __launch_bounds__(256) void k4_scatter_kernel(
    const int* __restrict__ edge_index, const int* __restrict__ off,
    int* __restrict__ cur, int2* __restrict__ de) {
  int e = blockIdx.x * 256 + threadIdx.x;
  if (e < N_EDGE) {
    int src = edge_index[e * 2 + 0];
    int dst = edge_index[e * 2 + 1];
    int pos = off[src] + atomicAdd(&cur[src], 1);
    de[pos] = make_int2(dst, e);
  }
}

// ==================================================================
// K5: segmented attention, single pass. qk stride 512; vw f32 from GEMM.
__global__ __launch_bounds__(256) void seg_attn_kernel(
    const u16* __restrict__ qkv, const float* __restrict__ bias,
    const int* __restrict__ off, const int2* __restrict__ de,
    const float* __restrict__ vw, const float* __restrict__ edge_diff,
    const float* __restrict__ bf1, const float* __restrict__ bf2,
    const float* __restrict__ bf3, float* __restrict__ out) {
  int wv = threadIdx.x >> 6, lane = threadIdx.x & 63;
  int src = blockIdx.x * 4 + wv;
  int h = lane & 15, eslot = lane >> 4;
  int lo = off[src];
  int deg = off[src + 1] - lo;
  const uint4* qp = (const uint4*)(qkv + (size_t)src * 512 + h * 16);
  uint4 q0 = qp[0], q1 = qp[1];
  float exsum = 0.f, a0 = 0.f, a1 = 0.f, a2 = 0.f;
  for (int ei = eslot; ei < deg; ei += 4) {
    int2 d_e = de[lo + ei];
    const uint4* kp = (const uint4*)(qkv + (size_t)d_e.x * 512 + 256 + h * 16);
    float d = dot8(q0, kp[0]) + dot8(q1, kp[1]);
    float ex = __expf(d + bias[(size_t)d_e.y * HEADS + h]);
    exsum += ex;
    const float* vp = vw + (size_t)d_e.x * 48 + h * 3;
    const float* dp = edge_diff + (size_t)d_e.y * 3;
    a0 += ex * vp[0] * dp[0];
    a1 += ex * vp[1] * dp[1];
    a2 += ex * vp[2] * dp[2];
  }
  exsum += __shfl_xor(exsum, 16);
  exsum += __shfl_xor(exsum, 32);
  float rden = (exsum > 0.f) ? 1.0f / exsum : 0.f;
  a0 *= rden; a1 *= rden; a2 *= rden;
  #pragma unroll
  for (int o = 1; o < 64; o <<= 1) {
    a0 += __shfl_xor(a0, o);
    a1 += __shfl_xor(a1, o);
    a2 += __shfl_xor(a2, o);
  }
  if (lane == 0) {
    out[src * 3 + 0] = a0 + bf1[0];
    out[src * 3 + 1] = a1 + bf2[0];
    out[src * 3 + 2] = a2 + bf3[0];
  }
}

// ==================================================================
extern "C" void kernel_launch(void* const* d_in, const int* in_sizes, int n_in,
                              void* d_out, int out_size, void* d_ws,
                              size_t ws_size, hipStream_t stream) {
  const float* query      = (const float*)d_in[0];
  const int*   edge_index = (const int*)d_in[1];
  const float* edge_diff  = (const float*)d_in[2];
  const float* pair       = (const float*)d_in[3];
  const float* ln_w       = (const float*)d_in[4];
  const float* ln_b       = (const float*)d_in[5];
  const float* pln_w      = (const float*)d_in[6];
  const float* pln_b      = (const float*)d_in[7];
  const float* Wq         = (const float*)d_in[8];
  const float* Wk         = (const float*)d_in[9];
  const float* Wv         = (const float*)d_in[10];
  const float* Wb         = (const float*)d_in[11];
  const float* bb         = (const float*)d_in[12];
  const float* Wf1        = (const float*)d_in[13];
  const float* bf1        = (const float*)d_in[14];
  const float* Wf2        = (const float*)d_in[15];
  const float* bf2        = (const float*)d_in[16];
  const float* Wf3        = (const float*)d_in[17];
  const float* bf3        = (const float*)d_in[18];

  char* ws = (char*)d_ws;
  u16*   qkv   = (u16*)(ws + WS_QKV);
  u16*   qn    = (u16*)(ws + WS_QN);
  u16*   WbfAll= (u16*)(ws + WS_WBF);
  float* bias  = (float*)(ws + WS_BIAS);
  float* vw    = (float*)(ws + WS_VW);
  int*   counts= (int*)(ws + WS_CNT);
  int*   cur   = (int*)(ws + WS_CUR);
  int*   off   = (int*)(ws + WS_OFF);
  int2*  de    = (int2*)(ws + WS_DE);
  float* out   = (float*)d_out;

  hipMemsetAsync(ws + WS_CNT, 0, 160000, stream);
  k1_pre_hist_bias_kernel<<<9088, 256, 0, stream>>>(
      query, ln_w, ln_b, qn, Wq, Wk, Wv, WbfAll, pln_w, pln_b, Wb, bb, Wf1,
      Wf2, Wf3, edge_index, counts, pair, bias);
  k2_gemm_scan_kernel<<<786, 256, 0, stream>>>(qn, WbfAll, qkv, vw, counts,
                                               off);
  k4_scatter_kernel<<<782, 256, 0, stream>>>(edge_index, off, cur, de);
  seg_attn_kernel<<<N_NODE / 4, 256, 0, stream>>>(qkv, bias, off, de, vw,
                                                  edge_diff, bf1, bf2, bf3,
                                                  out);
}